// Round 3
// baseline (314.054 us; speedup 1.0000x reference)
//
#include <hip/hip_runtime.h>

// ---------------------------------------------------------------------------
// CMSFlipLinear: y = x @ W^T, W = ternary * per-128-group scales.
// Round 3: 256x256 8-phase bf16 GEMM with mfma_f32_32x32x16_bf16
// (15% better MFMA-pipe efficiency than 16x16x32: m119 2495 vs 2176 TF),
// even 12/4/4/4 ds_read distribution, re-derived race-free stage map,
// vmcnt(4) at P4/P8. T1 XCD swizzle, T2 XOR swizzle (0 conflicts in R2),
// T5 setprio. M=8192, N=4096, K=4096.
// ---------------------------------------------------------------------------

using bf16x8 = __attribute__((ext_vector_type(8))) short;
using f32x16 = __attribute__((ext_vector_type(16))) float;
using u16x4  = __attribute__((ext_vector_type(4))) unsigned short;
using u16x8  = __attribute__((ext_vector_type(8))) unsigned short;

constexpr int K = 4096;
constexpr int N = 4096;

__device__ __forceinline__ unsigned short f2bf(float f) {
  unsigned u = __float_as_uint(f);
  u += 0x7FFFu + ((u >> 16) & 1u);
  return (unsigned short)(u >> 16);
}

__device__ __forceinline__ void gload_lds16(const void* gsrc, void* ldst) {
  const __attribute__((address_space(1))) unsigned* g =
      reinterpret_cast<const __attribute__((address_space(1))) unsigned*>(
          reinterpret_cast<uintptr_t>(gsrc));
  __attribute__((address_space(3))) unsigned* l =
      reinterpret_cast<__attribute__((address_space(3))) unsigned*>(
          reinterpret_cast<uintptr_t>(ldst));
  __builtin_amdgcn_global_load_lds(g, l, 16, 0, 0);
}

// ---- prep 1: x fp32 -> bf16 ------------------------------------------------
__global__ void cvt_x_kernel(const float* __restrict__ x,
                             unsigned short* __restrict__ o, long n4) {
  long t = (long)blockIdx.x * blockDim.x + threadIdx.x;
  if (t >= n4) return;
  float4 v = reinterpret_cast<const float4*>(x)[t];
  u16x4 r = {f2bf(v.x), f2bf(v.y), f2bf(v.z), f2bf(v.w)};
  reinterpret_cast<u16x4*>(o)[t] = r;
}

// ---- prep 2: W = ternary * scales -> bf16 ---------------------------------
__global__ void dequant_kernel(const int* __restrict__ w,
                               const float* __restrict__ s,
                               unsigned short* __restrict__ o, long n8) {
  long t = (long)blockIdx.x * blockDim.x + threadIdx.x;
  if (t >= n8) return;
  long e = t * 8;
  float sc = s[e >> 7];
  int4 a = reinterpret_cast<const int4*>(w + e)[0];
  int4 b = reinterpret_cast<const int4*>(w + e)[1];
  u16x8 r = {f2bf((float)a.x * sc), f2bf((float)a.y * sc),
             f2bf((float)a.z * sc), f2bf((float)a.w * sc),
             f2bf((float)b.x * sc), f2bf((float)b.y * sc),
             f2bf((float)b.z * sc), f2bf((float)b.w * sc)};
  *reinterpret_cast<u16x8*>(o + e) = r;
}

// ---------------------------------------------------------------------------
// LDS layout (shorts): a0 [0,16384) | b0 [16384,32768) | a1 [32768,49152)
//                      | b1 [49152,65536).
// Swizzle (shorts): idx = row*64 + (col ^ ((row&7)<<3)).  Involution; applied
// on the ds_read side AND on the global source of the linear-dest
// global_load_lds (rule #21: both-sides-or-neither). 0 conflicts in R2.
// ---------------------------------------------------------------------------

__device__ __forceinline__ bf16x8 ldfrag(const short* region, int row, int col) {
  return *reinterpret_cast<const bf16x8*>(region + row * 64 +
                                          (col ^ ((row & 7) << 3)));
}

// Stage one half-tile (128 rows x 64 cols bf16 = 16 KiB) at K-offset k0,
// half h, into LDS region. 2 global_load_lds_dwordx4 per thread.
__device__ __forceinline__ void stage_half(const short* gmat, short* lregion,
                                           int k0, int h, int wid, int l) {
#pragma unroll
  for (int load = 0; load < 2; ++load) {
    const int row = h * 128 + load * 64 + wid * 8 + (l >> 3);
    const int col = ((l & 7) ^ (l >> 3)) << 3;  // inverse-swizzled source col
    const short* g = gmat + (long)row * K + k0 + col;
    short* ldst = lregion + h * 8192 + load * 4096 + wid * 512;  // wave-uniform
    gload_lds16(g, ldst);
  }
}

// A fragments for one 32-row m-tile: 4 k-frags (K=64), row = lane&31,
// k = (lane>>5)*8 within each 16-wide k-frag.
__device__ __forceinline__ void loadA32(bf16x8 (&afr)[4], const short* ar,
                                        int wr, int mt, int ln31, int khalf) {
#pragma unroll
  for (int kf = 0; kf < 4; ++kf)
    afr[kf] = ldfrag(ar, wr * 128 + mt * 32 + ln31, kf * 16 + khalf * 8);
}

__device__ __forceinline__ void loadB32(bf16x8 (&bfr)[2][4], const short* br,
                                        int wc, int ln31, int khalf) {
#pragma unroll
  for (int nt = 0; nt < 2; ++nt)
#pragma unroll
    for (int kf = 0; kf < 4; ++kf)
      bfr[nt][kf] = ldfrag(br, wc * 64 + nt * 32 + ln31, kf * 16 + khalf * 8);
}

template <int MT>
__device__ __forceinline__ void mma32(f32x16 (&acc)[4][2], bf16x8 (&afr)[4],
                                      bf16x8 (&bfr)[2][4]) {
  __builtin_amdgcn_s_setprio(1);
#pragma unroll
  for (int kf = 0; kf < 4; ++kf)
#pragma unroll
    for (int nt = 0; nt < 2; ++nt)
      acc[MT][nt] = __builtin_amdgcn_mfma_f32_32x32x16_bf16(
          afr[kf], bfr[nt][kf], acc[MT][nt], 0, 0, 0);
  __builtin_amdgcn_s_setprio(0);
}

#define FENCE asm volatile("" ::: "memory")
#define BAR                        \
  do {                             \
    __builtin_amdgcn_s_barrier();  \
    FENCE;                         \
  } while (0)
#define LGKM0  asm volatile("s_waitcnt lgkmcnt(0)" ::: "memory")
#define VMCNT4 asm volatile("s_waitcnt vmcnt(4)" ::: "memory")
#define VMCNT0 asm volatile("s_waitcnt vmcnt(0)" ::: "memory")

// ---- 256x256 8-phase GEMM: C[M][N] = A[M][K] * B[N][K]^T -------------------
// 8 waves (2M x 4N), per-wave 128x64 = 4x2 tiles of 32x32 (acc f32x16).
// Reads: P1: B(8)+A-m0(4) | P2: A-m1 | P3: A-m2 | P4: A-m3  (12/4/4/4).
// Stages (race-free: region's last read drained >=1 barrier before stage):
//   P1: a1-lo(T1)  P2: a1-hi(T1)  P3: b0-lo(T2)  P4: b0-hi(T2)
//   P5: a0-lo(T2)  P6: a0-hi(T2)  P7: b1-lo(T3)  P8: b1-hi(T3)
// vmcnt(4) at P4 (a1+prev-b1 landed, b0 pair in flight) and P8 (b0+a0
// landed, b1 pair in flight).
__global__ __launch_bounds__(512) void gemm8p(const short* __restrict__ A,
                                              const short* __restrict__ B,
                                              float* __restrict__ C) {
  __shared__ short lds[65536];  // 128 KiB
  const int tid = threadIdx.x;
  const int wid = tid >> 6, l = tid & 63;
  const int wr = wid >> 2, wc = wid & 3;
  const int ln31 = l & 31, khalf = l >> 5;

  // T1: bijective XCD swizzle (512 blocks, 512%8==0)
  const int wg = blockIdx.x;
  const int swz = (wg & 7) * 64 + (wg >> 3);
  const long brow = (long)(swz >> 4) * 256;  // 32 M-tiles
  const long bcol = (long)(swz & 15) * 256;  // 16 N-tiles

  const short* gA = A + brow * K;
  const short* gB = B + bcol * K;
  short* a0 = lds;
  short* b0 = lds + 16384;
  short* a1 = lds + 32768;
  short* b1 = lds + 49152;

  // prologue: T0 (b0,a0) fully + T1's b1; FIFO order matters for vmcnt(4).
  stage_half(gB, b0, 0, 0, wid, l);
  stage_half(gB, b0, 0, 1, wid, l);
  stage_half(gA, a0, 0, 0, wid, l);
  stage_half(gA, a0, 0, 1, wid, l);
  stage_half(gB, b1, 64, 0, wid, l);
  stage_half(gB, b1, 64, 1, wid, l);
  VMCNT4;  // drain b0+a0; b1 (4 loads) in flight
  BAR;

  f32x16 acc[4][2] = {};
  bf16x8 afr[4], bfr[2][4];

#pragma unroll 1
  for (int it = 0; it < 31; ++it) {
    const int kt1 = (2 * it + 1) * 64, kt2 = kt1 + 64, kt3 = kt2 + 64;
    // ---- tile T0 = 2it (buf0) ----
    // P1
    loadB32(bfr, b0, wc, ln31, khalf);
    loadA32(afr, a0, wr, 0, ln31, khalf);
    stage_half(gA, a1, kt1, 0, wid, l);
    BAR; LGKM0;
    mma32<0>(acc, afr, bfr);
    BAR;
    // P2
    loadA32(afr, a0, wr, 1, ln31, khalf);
    stage_half(gA, a1, kt1, 1, wid, l);
    BAR; LGKM0;
    mma32<1>(acc, afr, bfr);
    BAR;
    // P3
    loadA32(afr, a0, wr, 2, ln31, khalf);
    stage_half(gB, b0, kt2, 0, wid, l);
    BAR; LGKM0;
    mma32<2>(acc, afr, bfr);
    BAR;
    // P4
    loadA32(afr, a0, wr, 3, ln31, khalf);
    stage_half(gB, b0, kt2, 1, wid, l);
    BAR; LGKM0;
    mma32<3>(acc, afr, bfr);
    VMCNT4;  // a1(T1) + prev b1 landed; b0(T2) pair in flight
    BAR;
    // ---- tile T1 = 2it+1 (buf1) ----
    // P5
    loadB32(bfr, b1, wc, ln31, khalf);
    loadA32(afr, a1, wr, 0, ln31, khalf);
    stage_half(gA, a0, kt2, 0, wid, l);
    BAR; LGKM0;
    mma32<0>(acc, afr, bfr);
    BAR;
    // P6
    loadA32(afr, a1, wr, 1, ln31, khalf);
    stage_half(gA, a0, kt2, 1, wid, l);
    BAR; LGKM0;
    mma32<1>(acc, afr, bfr);
    BAR;
    // P7
    loadA32(afr, a1, wr, 2, ln31, khalf);
    stage_half(gB, b1, kt3, 0, wid, l);
    BAR; LGKM0;
    mma32<2>(acc, afr, bfr);
    BAR;
    // P8
    loadA32(afr, a1, wr, 3, ln31, khalf);
    stage_half(gB, b1, kt3, 1, wid, l);
    BAR; LGKM0;
    mma32<3>(acc, afr, bfr);
    VMCNT4;  // b0+a0 (T2) landed; b1(T3) pair in flight
    BAR;
  }

  // ---- epilogue: T62 (buf0) + T63 (buf1) ----
  {
    // P1
    loadB32(bfr, b0, wc, ln31, khalf);
    loadA32(afr, a0, wr, 0, ln31, khalf);
    stage_half(gA, a1, 4032, 0, wid, l);  // a1(T63)
    BAR; LGKM0;
    mma32<0>(acc, afr, bfr);
    BAR;
    // P2
    loadA32(afr, a0, wr, 1, ln31, khalf);
    stage_half(gA, a1, 4032, 1, wid, l);
    BAR; LGKM0;
    mma32<1>(acc, afr, bfr);
    BAR;
    // P3
    loadA32(afr, a0, wr, 2, ln31, khalf);
    BAR; LGKM0;
    mma32<2>(acc, afr, bfr);
    BAR;
    // P4
    loadA32(afr, a0, wr, 3, ln31, khalf);
    BAR; LGKM0;
    mma32<3>(acc, afr, bfr);
    VMCNT0;  // drain a1(T63) + b1 leftovers
    BAR;
    // T63: no more LDS writers; plain reads + mma
    loadB32(bfr, b1, wc, ln31, khalf);
    loadA32(afr, a1, wr, 0, ln31, khalf);
    mma32<0>(acc, afr, bfr);
    loadA32(afr, a1, wr, 1, ln31, khalf);
    mma32<1>(acc, afr, bfr);
    loadA32(afr, a1, wr, 2, ln31, khalf);
    mma32<2>(acc, afr, bfr);
    loadA32(afr, a1, wr, 3, ln31, khalf);
    mma32<3>(acc, afr, bfr);
  }

  // C-write. 32x32 C/D layout (m74/m101): col = lane&31,
  // row = (reg&3) + 8*(reg>>2) + 4*(lane>>5).
  const long ccol = bcol + wc * 64 + ln31;
  const long crow0 = brow + wr * 128 + 4 * khalf;
#pragma unroll
  for (int mt = 0; mt < 4; ++mt)
#pragma unroll
    for (int nt = 0; nt < 2; ++nt)
#pragma unroll
      for (int r = 0; r < 16; ++r) {
        const long row = crow0 + mt * 32 + (r & 3) + 8 * (r >> 2);
        C[row * N + ccol + nt * 32] = acc[mt][nt][r];
      }
}

// ---- fallback (only if workspace too small): naive fp32 --------------------
__global__ void fallback_kernel(const float* __restrict__ x,
                                const int* __restrict__ t,
                                const float* __restrict__ s,
                                float* __restrict__ y) {
  int n = blockIdx.x * 256 + threadIdx.x;
  int m = blockIdx.y;
  const int* tr = t + (long)n * K;
  const float* xr = x + (long)m * K;
  float acc = 0.f;
  for (int g = 0; g < K / 128; ++g) {
    float sc = s[n * (K / 128) + g];
    float part = 0.f;
#pragma unroll 4
    for (int k = g * 128; k < g * 128 + 128; ++k)
      part += xr[k] * (float)tr[k];
    acc += part * sc;
  }
  y[(long)m * N + n] = acc;
}

extern "C" void kernel_launch(void* const* d_in, const int* in_sizes, int n_in,
                              void* d_out, int out_size, void* d_ws,
                              size_t ws_size, hipStream_t stream) {
  const float* x = (const float*)d_in[0];
  const int* tern = (const int*)d_in[1];
  const float* scales = (const float*)d_in[2];
  float* out = (float*)d_out;

  const long M = (long)in_sizes[0] / K;  // 8192
  const size_t needA = (size_t)M * K * sizeof(short);  // 64 MiB
  const size_t needB = (size_t)N * K * sizeof(short);  // 32 MiB

  if (ws_size >= needA + needB && (M % 256) == 0) {
    short* Abf = (short*)d_ws;
    short* Bbf = (short*)((char*)d_ws + needA);

    long n4 = M * K / 4;
    cvt_x_kernel<<<(unsigned)((n4 + 255) / 256), 256, 0, stream>>>(
        x, (unsigned short*)Abf, n4);

    long n8 = (long)N * K / 8;
    dequant_kernel<<<(unsigned)((n8 + 255) / 256), 256, 0, stream>>>(
        tern, scales, (unsigned short*)Bbf, n8);

    const unsigned nblk = (unsigned)((M / 256) * (N / 256));  // 512
    gemm8p<<<nblk, 512, 0, stream>>>(Abf, Bbf, out);
  } else {
    dim3 grid(N / 256, (unsigned)M);
    fallback_kernel<<<grid, 256, 0, stream>>>(x, tern, scales, out);
  }
}